// Round 18
// baseline (345.493 us; speedup 1.0000x reference)
//
#include <hip/hip_runtime.h>
#include <hip/hip_fp16.h>

#define N_NODES 50000
#define N_EDGES 800000
#define HID 128
#define OUTD 10
#define NGRAPH 128
#define CAP 64
#define OVF_MAX 4096
#define GBM 64
#define EPT 4           // edges/thread; 391 blocks * 256 * 4 >= 400000 per half

typedef __attribute__((ext_vector_type(8))) short short8;
typedef __attribute__((ext_vector_type(4))) float f32x4;

__device__ __forceinline__ int ld_idx(const int* p, int i, int is64) {
  return is64 ? p[2 * i] : p[i];
}

// ---------- rne fp32 -> bf16 split ----------
__device__ __forceinline__ void split1(float v, unsigned& hb, unsigned& lb) {
  unsigned u = __float_as_uint(v);
  hb = (u + 0x7FFFu + ((u >> 16) & 1u)) >> 16;
  float r = v - __uint_as_float(hb << 16);
  unsigned ur = __float_as_uint(r);
  lb = (ur + 0x7FFFu + ((ur >> 16) & 1u)) >> 16;
}

__device__ __forceinline__ float4 h4_to_f4(uint2 u) {
  __half2 a = *(__half2*)&u.x;
  __half2 b = *(__half2*)&u.y;
  float2 fa = __half22float2(a);
  float2 fb = __half22float2(b);
  return make_float4(fa.x, fa.y, fb.x, fb.y);
}

// ---------- setup ----------
__global__ __launch_bounds__(256) void setup_kernel(const int* __restrict__ ei,
                                                    const float* __restrict__ W_in,
                                                    const float* __restrict__ W_hops,
                                                    const float* __restrict__ Wc,
                                                    const float* __restrict__ b4,
                                                    const float* __restrict__ bc,
                                                    int* __restrict__ flag,
                                                    unsigned short* __restrict__ WhiT,
                                                    unsigned short* __restrict__ WloT,
                                                    float* __restrict__ Wf,
                                                    float* __restrict__ bf) {
  int b = blockIdx.x;
  int tid = threadIdx.x;
  if (b == 0) {
    if (tid == 0) {
      int all0 = 1;
      for (int i = 0; i < 64; ++i) {
        if (ei[2 * i + 1] != 0) { all0 = 0; break; }
      }
      flag[0] = all0;
    }
  } else if (b <= 4) {
    int m = b - 1;
    const float* W = (m == 0) ? W_in : (W_hops + (size_t)(m - 1) * HID * HID);
    unsigned short* oh = WhiT + (size_t)m * HID * HID;
    unsigned short* ol = WloT + (size_t)m * HID * HID;
    for (int it = 0; it < 64; ++it) {
      int idx = it * 256 + tid;
      int k = idx >> 7, n = idx & 127;
      unsigned hb, lb;
      split1(W[k * HID + n], hb, lb);
      oh[n * HID + k] = (unsigned short)hb;
      ol[n * HID + k] = (unsigned short)lb;
    }
  } else {
    const float* W4 = W_hops + 3 * (size_t)HID * HID;
    for (int idx = tid; idx < HID * OUTD; idx += 256) {
      int k = idx / OUTD, o = idx % OUTD;
      float s = 0.f;
      for (int j = 0; j < HID; ++j) s += W4[k * HID + j] * Wc[j * OUTD + o];
      Wf[idx] = s;
    }
    if (tid < OUTD) {
      float s = bc[tid];
      for (int j = 0; j < HID; ++j) s += b4[j] * Wc[j * OUTD + tid];
      bf[tid] = s;
    }
  }
}

// ---------- MFMA GEMM body: A fp32 or fp16, C fp16 ----------
template <bool A16>
__device__ __forceinline__ void gemm_mfma_body(const void* __restrict__ Av,
                                               const unsigned short* __restrict__ WhT,
                                               const unsigned short* __restrict__ WlT,
                                               const float* __restrict__ bias,
                                               __half* __restrict__ C16,
                                               int M, int row0) {
  __shared__ unsigned short sBall[2 * 64 * HID];   // 32 KB
  unsigned short* sBhi = sBall;
  unsigned short* sBlo = sBall + 64 * HID;
  int tid = threadIdx.x;
  int w = tid >> 6, lane = tid & 63;
  int m = lane & 15, kq = lane >> 4;
  int arow = min(row0 + w * 16 + m, M - 1);

  short8 AH[4], AL[4];
#pragma unroll
  for (int kc4 = 0; kc4 < 4; ++kc4) {
    float av[8];
    if (A16) {
      const __half* Ap = (const __half*)Av + (size_t)arow * HID + kq * 8;
      uint4 raw = *(const uint4*)(Ap + kc4 * 32);
      float4 f0 = h4_to_f4(make_uint2(raw.x, raw.y));
      float4 f1 = h4_to_f4(make_uint2(raw.z, raw.w));
      av[0] = f0.x; av[1] = f0.y; av[2] = f0.z; av[3] = f0.w;
      av[4] = f1.x; av[5] = f1.y; av[6] = f1.z; av[7] = f1.w;
    } else {
      const float* Ap = (const float*)Av + (size_t)arow * HID + kq * 8;
      float4 a0 = *(const float4*)(Ap + kc4 * 32);
      float4 a1 = *(const float4*)(Ap + kc4 * 32 + 4);
      av[0] = a0.x; av[1] = a0.y; av[2] = a0.z; av[3] = a0.w;
      av[4] = a1.x; av[5] = a1.y; av[6] = a1.z; av[7] = a1.w;
    }
#pragma unroll
    for (int i = 0; i < 8; ++i) {
      unsigned hb, lb;
      split1(av[i], hb, lb);
      AH[kc4][i] = (short)hb;
      AL[kc4][i] = (short)lb;
    }
  }

  f32x4 acc[8];
#pragma unroll
  for (int j = 0; j < 8; ++j) acc[j] = (f32x4){0.f, 0.f, 0.f, 0.f};

#pragma unroll
  for (int half = 0; half < 2; ++half) {
    if (half) __syncthreads();
#pragma unroll
    for (int it = 0; it < 8; ++it) {
      int f = it * 256 + tid;
      int mat = f >> 10;
      int ln = (f >> 4) & 63;
      int c = f & 15;
      int cs = c ^ (ln & 15);
      const unsigned short* src = (mat ? WlT : WhT) + (size_t)(half * 64 + ln) * HID + c * 8;
      unsigned short* dst = (mat ? sBlo : sBhi) + ln * HID + cs * 8;
      *(uint4*)dst = *(const uint4*)src;
    }
    __syncthreads();

#pragma unroll
    for (int kc4 = 0; kc4 < 4; ++kc4) {
      int kc = kc4 * 4 + kq;
      int cs = kc ^ m;
#pragma unroll
      for (int jl = 0; jl < 4; ++jl) {
        int ln = jl * 16 + m;
        short8 bhi = *(const short8*)&sBhi[ln * HID + cs * 8];
        short8 blo = *(const short8*)&sBlo[ln * HID + cs * 8];
        int j = half * 4 + jl;
        acc[j] = __builtin_amdgcn_mfma_f32_16x16x32_bf16(AH[kc4], bhi, acc[j], 0, 0, 0);
        acc[j] = __builtin_amdgcn_mfma_f32_16x16x32_bf16(AL[kc4], bhi, acc[j], 0, 0, 0);
        acc[j] = __builtin_amdgcn_mfma_f32_16x16x32_bf16(AH[kc4], blo, acc[j], 0, 0, 0);
      }
    }
  }

  // epilogue: stage in LDS, coalesced fp16 stores
  __syncthreads();
  float* sC = (float*)sBall;
  int rloc = w * 16 + (lane >> 4) * 4;
#pragma unroll
  for (int j = 0; j < 8; ++j) {
    int col = j * 16 + m;
    float bv = bias ? bias[col] : 0.f;
#pragma unroll
    for (int r = 0; r < 4; ++r)
      sC[(rloc + r) * HID + col] = acc[j][r] + bv;
  }
  __syncthreads();
#pragma unroll
  for (int it = 0; it < 8; ++it) {
    int f = it * 256 + tid;
    int rr = f >> 5;
    int c4 = (f & 31) * 4;
    int grow = row0 + rr;
    if (grow < M) {
      float4 v = *(const float4*)&sC[rr * HID + c4];
      __half2 h0 = __floats2half2_rn(v.x, v.y);
      __half2 h1 = __floats2half2_rn(v.z, v.w);
      uint2 u;
      u.x = *(unsigned*)&h0;
      u.y = *(unsigned*)&h1;
      *(uint2*)(C16 + (size_t)grow * HID + c4) = u;
    }
  }
}

template <bool A16>
__global__ __launch_bounds__(256) void gemm_kernel(const void* __restrict__ A,
                                                   const unsigned short* __restrict__ WhT,
                                                   const unsigned short* __restrict__ WlT,
                                                   __half* __restrict__ C16, int M) {
  gemm_mfma_body<A16>(A, WhT, WlT, nullptr, C16, M, blockIdx.x * GBM);
}

// ---------- fill phase: 4 atomics in flight per thread (391 blocks cover a half) ----------
__device__ __forceinline__ void fill_phase(const int* __restrict__ ei,
                                           int* __restrict__ fillcnt,
                                           int* __restrict__ col_fixed,
                                           int* __restrict__ ovf_cnt,
                                           int* __restrict__ ovf,
                                           const int* __restrict__ flag,
                                           int e0, int e1) {
  int base = e0 + blockIdx.x * (256 * EPT);
  if (base >= e1) return;
  int is64 = flag[0];
  int tid = threadIdx.x;
  int dsts[EPT], srcs[EPT], pos[EPT];
#pragma unroll
  for (int u = 0; u < EPT; ++u) {
    int e = base + u * 256 + tid;
    if (e < e1) {
      dsts[u] = ld_idx(ei, N_EDGES + e, is64);
      srcs[u] = ld_idx(ei, e, is64);
    } else {
      dsts[u] = -1; srcs[u] = 0;
    }
  }
#pragma unroll
  for (int u = 0; u < EPT; ++u)
    pos[u] = (dsts[u] >= 0) ? atomicAdd(&fillcnt[dsts[u]], 1) : 0;
#pragma unroll
  for (int u = 0; u < EPT; ++u) {
    if (dsts[u] >= 0) {
      if (pos[u] < CAP) {
        col_fixed[dsts[u] * CAP + pos[u]] = srcs[u];
      } else {
        int o = atomicAdd(ovf_cnt, 1);
        if (o < OVF_MAX) { ovf[2 * o] = dsts[u]; ovf[2 * o + 1] = srcs[u]; }
      }
    }
  }
}

template <bool A16>
__global__ __launch_bounds__(256) void gemm_fill_kernel(const void* __restrict__ A,
                                                        const unsigned short* __restrict__ WhT,
                                                        const unsigned short* __restrict__ WlT,
                                                        const float* __restrict__ bias,
                                                        __half* __restrict__ C16,
                                                        const int* __restrict__ ei,
                                                        int* __restrict__ fillcnt,
                                                        int* __restrict__ col_fixed,
                                                        int* __restrict__ ovf_cnt,
                                                        int* __restrict__ ovf,
                                                        const int* __restrict__ flag,
                                                        int e0, int e1) {
  if (blockIdx.x & 1) {
    fill_phase(ei, fillcnt, col_fixed, ovf_cnt, ovf, flag, e0, e1);
    gemm_mfma_body<A16>(A, WhT, WlT, bias, C16, N_NODES, blockIdx.x * GBM);
  } else {
    gemm_mfma_body<A16>(A, WhT, WlT, bias, C16, N_NODES, blockIdx.x * GBM);
    fill_phase(ei, fillcnt, col_fixed, ovf_cnt, ovf, flag, e0, e1);
  }
}

// ---------- agg v8: 16-lane groups x 4 nbrs, uint4 loads, 3-deep rotating prefetch ----------
template <bool FIRST>
__global__ __launch_bounds__(256) void agg_kernel(const __half* __restrict__ xw,
                                                  const int* __restrict__ fillcnt,
                                                  const int* __restrict__ col_fixed,
                                                  float* __restrict__ ew,
                                                  const float* __restrict__ bias,
                                                  const int* __restrict__ ovf_cnt,
                                                  const int* __restrict__ ovf,
                                                  __half* __restrict__ out) {
  int wave = threadIdx.x >> 6;
  int lane = threadIdx.x & 63;
  int node = blockIdx.x * 4 + wave;
  if (node >= N_NODES) return;
  int g = lane >> 4;        // neighbor subgroup 0..3
  int q = lane & 15;        // uint4 chunk: features 8q..8q+7

  const uint4* x4 = (const uint4*)xw;   // row stride 16 (128 halves)
  int deg = fillcnt[node];
  int m = min(deg, CAP);
  float dd = rsqrtf(1.0f + (float)deg);
  float acc[8];
#pragma unroll
  for (int i = 0; i < 8; ++i) acc[i] = 0.f;

  if (g == 0) {             // self term + bias on features 8q..8q+7
    float sn = dd * dd;
    uint4 raw = x4[(size_t)node * 16 + q];
    float4 f0 = h4_to_f4(make_uint2(raw.x, raw.y));
    float4 f1 = h4_to_f4(make_uint2(raw.z, raw.w));
    float4 b0 = ((const float4*)bias)[2 * q];
    float4 b1 = ((const float4*)bias)[2 * q + 1];
    acc[0] = f0.x * sn + b0.x; acc[1] = f0.y * sn + b0.y;
    acc[2] = f0.z * sn + b0.z; acc[3] = f0.w * sn + b0.w;
    acc[4] = f1.x * sn + b1.x; acc[5] = f1.y * sn + b1.y;
    acc[6] = f1.z * sn + b1.z; acc[7] = f1.w * sn + b1.w;
  }

  int cidx = node;
  float cw = 0.f;
  if (lane < m) {
    cidx = col_fixed[node * CAP + lane];
    if (FIRST) {
      cw = rsqrtf(1.0f + (float)fillcnt[cidx]) * dd;
      ew[node * CAP + lane] = cw;
    } else {
      cw = ew[node * CAP + lane];
    }
  }

#define GFETCH(JJ, BUF, WB)                                                              \
  {                                                                                      \
    int _sg = min((JJ) + g, 63);                                                         \
    int _src = __builtin_amdgcn_ds_bpermute(_sg << 2, cidx);                             \
    WB = __uint_as_float((unsigned)__builtin_amdgcn_ds_bpermute(_sg << 2,                \
                                                                (int)__float_as_uint(cw))); \
    BUF = x4[(size_t)_src * 16 + q];                                                     \
  }

  if (m > 0) {
    uint4 b0, b1, b2;
    float w0, w1, w2;
    GFETCH(0, b0, w0);
    GFETCH(4, b1, w1);
    GFETCH(8, b2, w2);
    for (int jj = 0; jj < m; jj += 4) {
      const __half2* ph = (const __half2*)&b0;
#pragma unroll
      for (int t = 0; t < 4; ++t) {
        float2 f = __half22float2(ph[t]);
        acc[2 * t] = fmaf(f.x, w0, acc[2 * t]);
        acc[2 * t + 1] = fmaf(f.y, w0, acc[2 * t + 1]);
      }
      b0 = b1; w0 = w1;
      b1 = b2; w1 = w2;
      GFETCH(jj + 12, b2, w2);
    }
  }
#undef GFETCH

  if (deg > CAP && g == 0) {         // rare overflow fixup
    int novf = min(*ovf_cnt, OVF_MAX);
    for (int o = 0; o < novf; ++o) {
      if (ovf[2 * o] == node) {
        int src = ovf[2 * o + 1];
        float w = rsqrtf(1.0f + (float)fillcnt[src]) * dd;
        uint4 raw = x4[(size_t)src * 16 + q];
        const __half2* ph = (const __half2*)&raw;
#pragma unroll
        for (int t = 0; t < 4; ++t) {
          float2 f = __half22float2(ph[t]);
          acc[2 * t] = fmaf(f.x, w, acc[2 * t]);
          acc[2 * t + 1] = fmaf(f.y, w, acc[2 * t + 1]);
        }
      }
    }
  }

#pragma unroll
  for (int i = 0; i < 8; ++i) {
    acc[i] += __shfl_xor(acc[i], 16, 64);
    acc[i] += __shfl_xor(acc[i], 32, 64);
  }

  if (g == 0) {
#pragma unroll
    for (int i = 0; i < 8; ++i) acc[i] = fmaxf(acc[i], 0.f);
    __half2 p0 = __floats2half2_rn(acc[0], acc[1]);
    __half2 p1 = __floats2half2_rn(acc[2], acc[3]);
    __half2 p2 = __floats2half2_rn(acc[4], acc[5]);
    __half2 p3 = __floats2half2_rn(acc[6], acc[7]);
    uint4 u;
    u.x = *(unsigned*)&p0; u.y = *(unsigned*)&p1;
    u.z = *(unsigned*)&p2; u.w = *(unsigned*)&p3;
    ((uint4*)out)[(size_t)node * 16 + q] = u;
  }
}

// ---------- z = h3 @ Wf (h fp16; sW reads wave-uniform -> broadcast) ----------
__global__ __launch_bounds__(256) void z_kernel(const __half* __restrict__ h,
                                                const float* __restrict__ Wf,
                                                float* __restrict__ z, int M) {
  __shared__ float sW[HID * OUTD];
  int tid = threadIdx.x;
  for (int i = tid; i < HID * OUTD; i += 256) sW[i] = Wf[i];
  __syncthreads();
  int row = blockIdx.x * 256 + tid;
  if (row >= M) return;
  float y[OUTD];
#pragma unroll
  for (int o = 0; o < OUTD; ++o) y[o] = 0.f;
  const uint4* hr = (const uint4*)(h + (size_t)row * HID);
  for (int k8 = 0; k8 < 16; ++k8) {
    uint4 raw = hr[k8];
    float4 h0 = h4_to_f4(make_uint2(raw.x, raw.y));
    float4 h1 = h4_to_f4(make_uint2(raw.z, raw.w));
    int kb = k8 * 8;
#pragma unroll
    for (int o = 0; o < OUTD; ++o) {
      y[o] += h0.x * sW[(kb + 0) * OUTD + o];
      y[o] += h0.y * sW[(kb + 1) * OUTD + o];
      y[o] += h0.z * sW[(kb + 2) * OUTD + o];
      y[o] += h0.w * sW[(kb + 3) * OUTD + o];
      y[o] += h1.x * sW[(kb + 4) * OUTD + o];
      y[o] += h1.y * sW[(kb + 5) * OUTD + o];
      y[o] += h1.z * sW[(kb + 6) * OUTD + o];
      y[o] += h1.w * sW[(kb + 7) * OUTD + o];
    }
  }
#pragma unroll
  for (int o = 0; o < OUTD; ++o) z[(size_t)row * OUTD + o] = y[o];
}

// ---------- last hop in 10-dim + pooling + fused finalize (done-counter) ----------
__global__ __launch_bounds__(256) void agg10_kernel(const float* __restrict__ z,
                                                    const int* __restrict__ fillcnt,
                                                    const int* __restrict__ col_fixed,
                                                    const float* __restrict__ ew,
                                                    const float* __restrict__ bf,
                                                    const int* __restrict__ ovf_cnt,
                                                    const int* __restrict__ ovf,
                                                    const int* __restrict__ batch,
                                                    float* __restrict__ pool,
                                                    float* __restrict__ cnt,
                                                    const int* __restrict__ flag,
                                                    int* __restrict__ done_cnt,
                                                    float* __restrict__ out) {
  __shared__ float spool[NGRAPH * OUTD];
  __shared__ float scount[NGRAPH];
  __shared__ int lastflag;
  int tid = threadIdx.x;
  for (int i = tid; i < NGRAPH * OUTD; i += 256) spool[i] = 0.f;
  if (tid < NGRAPH) scount[tid] = 0.f;
  __syncthreads();

  int is64 = flag[0];
  int node = blockIdx.x * 256 + tid;
  bool valid = node < N_NODES;
  int nc = valid ? node : (N_NODES - 1);
  int g = ld_idx(batch, nc, is64);

  float acc[OUTD];
#pragma unroll
  for (int o = 0; o < OUTD; ++o) acc[o] = 0.f;
  float c = 0.f;

  if (valid) {
    int deg = fillcnt[node];
    float sn = 1.0f / (1.0f + (float)deg);
#pragma unroll
    for (int o = 0; o < OUTD; ++o) acc[o] = z[(size_t)node * OUTD + o] * sn + bf[o];
    c = 1.f;

    int m = min(deg, CAP);
    for (int j = 0; j < m; ++j) {
      int src = col_fixed[node * CAP + j];
      float w = ew[node * CAP + j];
      const float2* zr = (const float2*)(z + (size_t)src * OUTD);
#pragma unroll
      for (int p = 0; p < 5; ++p) {
        float2 u = zr[p];
        acc[2 * p] += u.x * w;
        acc[2 * p + 1] += u.y * w;
      }
    }
    if (deg > CAP) {
      int novf = min(*ovf_cnt, OVF_MAX);
      float dd = rsqrtf(1.0f + (float)deg);
      for (int o = 0; o < novf; ++o) {
        if (ovf[2 * o] == node) {
          int src = ovf[2 * o + 1];
          float w = rsqrtf(1.0f + (float)fillcnt[src]) * dd;
#pragma unroll
          for (int qq = 0; qq < OUTD; ++qq) acc[qq] += z[(size_t)src * OUTD + qq] * w;
        }
      }
    }
  }

  int g0 = __builtin_amdgcn_readfirstlane(g);
  unsigned long long same = __ballot(g == g0);
  unsigned long long act = __ballot(1);
  if (same == act) {
#pragma unroll
    for (int off = 1; off < 64; off <<= 1) {
#pragma unroll
      for (int o = 0; o < OUTD; ++o) acc[o] += __shfl_xor(acc[o], off, 64);
      c += __shfl_xor(c, off, 64);
    }
    if ((tid & 63) == 0) {
#pragma unroll
      for (int o = 0; o < OUTD; ++o) atomicAdd(&spool[g0 * OUTD + o], acc[o]);
      atomicAdd(&scount[g0], c);
    }
  } else if (valid) {
#pragma unroll
    for (int o = 0; o < OUTD; ++o) atomicAdd(&spool[g * OUTD + o], acc[o]);
    atomicAdd(&scount[g], 1.f);
  }
  __syncthreads();
  for (int i = tid; i < NGRAPH * OUTD; i += 256) {
    float v = spool[i];
    if (v != 0.f) atomicAdd(&pool[i], v);
  }
  if (tid < NGRAPH && scount[tid] != 0.f) atomicAdd(&cnt[tid], scount[tid]);

  // fused finalize: last block to finish computes the output
  __threadfence();
  if (tid == 0) {
    int t = atomicAdd(done_cnt, 1);
    lastflag = (t == (int)gridDim.x - 1);
  }
  __syncthreads();
  if (lastflag) {
    __threadfence();
    for (int i = tid; i < NGRAPH * OUTD; i += 256) {
      float cc = cnt[i / OUTD];
      out[i] = pool[i] / fmaxf(cc, 1.0f);
    }
  }
}

extern "C" void kernel_launch(void* const* d_in, const int* in_sizes, int n_in,
                              void* d_out, int out_size, void* d_ws, size_t ws_size,
                              hipStream_t stream) {
  const float* x      = (const float*)d_in[0];
  const int*   ei     = (const int*)d_in[1];
  const int*   batch  = (const int*)d_in[2];
  const float* W_in   = (const float*)d_in[3];
  const float* b_in   = (const float*)d_in[4];
  const float* W_hops = (const float*)d_in[5];
  const float* b_hops = (const float*)d_in[6];
  const float* W_cls  = (const float*)d_in[7];
  const float* b_cls  = (const float*)d_in[8];
  float* out = (float*)d_out;

  char* ws = (char*)d_ws;
  size_t off = 0;
  auto alloc = [&](size_t bytes) -> void* {
    void* p = ws + off;
    off += (bytes + 255) & ~(size_t)255;
    return p;
  };

  // zero-initialized region first
  int*   fillcnt = (int*)alloc(N_NODES * 4);
  int*   ovf_cnt = (int*)alloc(4);
  float* pool    = (float*)alloc(NGRAPH * OUTD * 4);
  float* cnt     = (float*)alloc(NGRAPH * 4);
  int*   done_cnt = (int*)alloc(4);
  size_t zero_bytes = off;
  int*   flag    = (int*)alloc(4);
  int*   ovf     = (int*)alloc(OVF_MAX * 2 * 4);
  int*   col_fixed = (int*)alloc((size_t)N_NODES * CAP * 4);
  float* ew      = (float*)alloc((size_t)N_NODES * CAP * 4);
  __half* bufH   = (__half*)alloc((size_t)N_NODES * HID * 2);    // h (fp16)
  __half* bufX   = (__half*)alloc((size_t)N_NODES * HID * 2);    // xw (fp16)
  float* z       = (float*)alloc((size_t)N_NODES * OUTD * 4);
  float* Wf      = (float*)alloc(HID * OUTD * 4);
  float* bf      = (float*)alloc(16 * 4);
  unsigned short* WhiT = (unsigned short*)alloc(4 * HID * HID * 2);
  unsigned short* WloT = (unsigned short*)alloc(4 * HID * HID * 2);
  (void)ws_size; (void)in_sizes; (void)n_in; (void)out_size;

  hipMemsetAsync(d_ws, 0, zero_bytes, stream);
  setup_kernel<<<6, 256, 0, stream>>>(ei, W_in, W_hops, W_cls,
                                      b_hops + 3 * HID, b_cls,
                                      flag, WhiT, WloT, Wf, bf);

  const int gblocks = (N_NODES + GBM - 1) / GBM;   // 782
  const int ablocks = (N_NODES + 3) / 4;
  const int EHALF = N_EDGES / 2;
  const int WW = HID * HID;

  // encoder (x fp32 -> h0 fp16) + first half of edge placement
  gemm_fill_kernel<false><<<gblocks, 256, 0, stream>>>(x, WhiT, WloT, b_in, bufH,
                                                       ei, fillcnt, col_fixed, ovf_cnt, ovf,
                                                       flag, 0, EHALF);
  // hop-1 GEMM (h0 fp16 -> xw1 fp16) + second half of edge placement
  gemm_fill_kernel<true><<<gblocks, 256, 0, stream>>>(bufH, WhiT + WW, WloT + WW, nullptr,
                                                      bufX,
                                                      ei, fillcnt, col_fixed, ovf_cnt, ovf,
                                                      flag, EHALF, N_EDGES);
  // hop 1 aggregate (builds ew)
  agg_kernel<true><<<ablocks, 256, 0, stream>>>(bufX, fillcnt, col_fixed, ew,
                                                b_hops, ovf_cnt, ovf, bufH);
  // hop 2
  gemm_kernel<true><<<gblocks, 256, 0, stream>>>(bufH, WhiT + 2 * WW, WloT + 2 * WW,
                                                 bufX, N_NODES);
  agg_kernel<false><<<ablocks, 256, 0, stream>>>(bufX, fillcnt, col_fixed, ew,
                                                 b_hops + HID, ovf_cnt, ovf, bufH);
  // hop 3
  gemm_kernel<true><<<gblocks, 256, 0, stream>>>(bufH, WhiT + 3 * WW, WloT + 3 * WW,
                                                 bufX, N_NODES);
  agg_kernel<false><<<ablocks, 256, 0, stream>>>(bufX, fillcnt, col_fixed, ew,
                                                 b_hops + 2 * HID, ovf_cnt, ovf, bufH);
  // z = relu(h3) @ Wf (relu already applied in agg)
  int nb = (N_NODES + 255) / 256;
  z_kernel<<<nb, 256, 0, stream>>>(bufH, Wf, z, N_NODES);
  // hop 4 folded through classifier in 10-dim + pooling + fused finalize
  agg10_kernel<<<nb, 256, 0, stream>>>(z, fillcnt, col_fixed, ew, bf,
                                       ovf_cnt, ovf, batch, pool, cnt, flag,
                                       done_cnt, out);
}

// Round 19
// 337.274 us; speedup vs baseline: 1.0244x; 1.0244x over previous
//
#include <hip/hip_runtime.h>
#include <hip/hip_fp16.h>

#define N_NODES 50000
#define N_EDGES 800000
#define HID 128
#define OUTD 10
#define NGRAPH 128
#define CAP 64
#define OVF_MAX 4096
#define GBM 64
#define EPT 4           // edges/thread; blocks*256*4 covers each half

typedef __attribute__((ext_vector_type(8))) _Float16 half8;
typedef __attribute__((ext_vector_type(4))) float f32x4;

__device__ __forceinline__ int ld_idx(const int* p, int i, int is64) {
  return is64 ? p[2 * i] : p[i];
}

__device__ __forceinline__ float4 h4_to_f4(uint2 u) {
  __half2 a = *(__half2*)&u.x;
  __half2 b = *(__half2*)&u.y;
  float2 fa = __half22float2(a);
  float2 fb = __half22float2(b);
  return make_float4(fa.x, fa.y, fb.x, fb.y);
}

// ---------- setup: flag probe; W -> exact fp16 hi/lo, transposed [n][k]; fold W4@Wc ----------
__global__ __launch_bounds__(256) void setup_kernel(const int* __restrict__ ei,
                                                    const float* __restrict__ W_in,
                                                    const float* __restrict__ W_hops,
                                                    const float* __restrict__ Wc,
                                                    const float* __restrict__ b4,
                                                    const float* __restrict__ bc,
                                                    int* __restrict__ flag,
                                                    unsigned short* __restrict__ WhiT,
                                                    unsigned short* __restrict__ WloT,
                                                    float* __restrict__ Wf,
                                                    float* __restrict__ bf) {
  int b = blockIdx.x;
  int tid = threadIdx.x;
  if (b == 0) {
    if (tid == 0) {
      int all0 = 1;
      for (int i = 0; i < 64; ++i) {
        if (ei[2 * i + 1] != 0) { all0 = 0; break; }
      }
      flag[0] = all0;
    }
  } else if (b <= 4) {
    int m = b - 1;
    const float* W = (m == 0) ? W_in : (W_hops + (size_t)(m - 1) * HID * HID);
    unsigned short* oh = WhiT + (size_t)m * HID * HID;
    unsigned short* ol = WloT + (size_t)m * HID * HID;
    for (int it = 0; it < 64; ++it) {
      int idx = it * 256 + tid;
      int k = idx >> 7, n = idx & 127;
      float w = W[k * HID + n];
      __half wh = __float2half_rn(w);
      __half wl = __float2half_rn(w - __half2float(wh));
      oh[n * HID + k] = *(unsigned short*)&wh;
      ol[n * HID + k] = *(unsigned short*)&wl;
    }
  } else {
    const float* W4 = W_hops + 3 * (size_t)HID * HID;
    for (int idx = tid; idx < HID * OUTD; idx += 256) {
      int k = idx / OUTD, o = idx % OUTD;
      float s = 0.f;
      for (int j = 0; j < HID; ++j) s += W4[k * HID + j] * Wc[j * OUTD + o];
      Wf[idx] = s;
    }
    if (tid < OUTD) {
      float s = bc[tid];
      for (int j = 0; j < HID; ++j) s += b4[j] * Wc[j * OUTD + tid];
      bf[tid] = s;
    }
  }
}

// ---------- MFMA GEMM body: native f16 MFMA, A fp32(cvt) or fp16(direct), C fp16 ----------
template <bool A16>
__device__ __forceinline__ void gemm_mfma_body(const void* __restrict__ Av,
                                               const unsigned short* __restrict__ WhT,
                                               const unsigned short* __restrict__ WlT,
                                               const float* __restrict__ bias,
                                               __half* __restrict__ C16,
                                               int M, int row0) {
  __shared__ unsigned short sBall[2 * 64 * HID];   // 32 KB: hi then lo
  unsigned short* sBhi = sBall;
  unsigned short* sBlo = sBall + 64 * HID;
  int tid = threadIdx.x;
  int w = tid >> 6, lane = tid & 63;
  int m = lane & 15, kq = lane >> 4;
  int arow = min(row0 + w * 16 + m, M - 1);

  // A fragments: 4 k-chunks of 8 halves
  half8 A8[4];
  if (A16) {
    const __half* Ap = (const __half*)Av + (size_t)arow * HID + kq * 8;
#pragma unroll
    for (int kc4 = 0; kc4 < 4; ++kc4)
      A8[kc4] = *(const half8*)(Ap + kc4 * 32);
  } else {
    const float* Ap = (const float*)Av + (size_t)arow * HID + kq * 8;
#pragma unroll
    for (int kc4 = 0; kc4 < 4; ++kc4) {
      float4 a0 = *(const float4*)(Ap + kc4 * 32);
      float4 a1 = *(const float4*)(Ap + kc4 * 32 + 4);
      half8 a;
      a[0] = (_Float16)a0.x; a[1] = (_Float16)a0.y;
      a[2] = (_Float16)a0.z; a[3] = (_Float16)a0.w;
      a[4] = (_Float16)a1.x; a[5] = (_Float16)a1.y;
      a[6] = (_Float16)a1.z; a[7] = (_Float16)a1.w;
      A8[kc4] = a;
    }
  }

  f32x4 acc[8];
#pragma unroll
  for (int j = 0; j < 8; ++j) acc[j] = (f32x4){0.f, 0.f, 0.f, 0.f};

#pragma unroll
  for (int half = 0; half < 2; ++half) {
    if (half) __syncthreads();
    // stage 64 cols x 128 k, hi+lo: 2048 uint4, 8 per thread
#pragma unroll
    for (int it = 0; it < 8; ++it) {
      int f = it * 256 + tid;
      int mat = f >> 10;
      int ln = (f >> 4) & 63;
      int c = f & 15;
      int cs = c ^ (ln & 15);
      const unsigned short* src = (mat ? WlT : WhT) + (size_t)(half * 64 + ln) * HID + c * 8;
      unsigned short* dst = (mat ? sBlo : sBhi) + ln * HID + cs * 8;
      *(uint4*)dst = *(const uint4*)src;
    }
    __syncthreads();

#pragma unroll
    for (int kc4 = 0; kc4 < 4; ++kc4) {
      int kc = kc4 * 4 + kq;
      int cs = kc ^ m;
#pragma unroll
      for (int jl = 0; jl < 4; ++jl) {
        int ln = jl * 16 + m;
        half8 bh = *(const half8*)&sBhi[ln * HID + cs * 8];
        half8 bl = *(const half8*)&sBlo[ln * HID + cs * 8];
        int j = half * 4 + jl;
        acc[j] = __builtin_amdgcn_mfma_f32_16x16x32_f16(A8[kc4], bh, acc[j], 0, 0, 0);
        acc[j] = __builtin_amdgcn_mfma_f32_16x16x32_f16(A8[kc4], bl, acc[j], 0, 0, 0);
      }
    }
  }

  // epilogue: stage in LDS, coalesced fp16 stores
  __syncthreads();
  float* sC = (float*)sBall;
  int rloc = w * 16 + (lane >> 4) * 4;
#pragma unroll
  for (int j = 0; j < 8; ++j) {
    int col = j * 16 + m;
    float bv = bias ? bias[col] : 0.f;
#pragma unroll
    for (int r = 0; r < 4; ++r)
      sC[(rloc + r) * HID + col] = acc[j][r] + bv;
  }
  __syncthreads();
#pragma unroll
  for (int it = 0; it < 8; ++it) {
    int f = it * 256 + tid;
    int rr = f >> 5;
    int c4 = (f & 31) * 4;
    int grow = row0 + rr;
    if (grow < M) {
      float4 v = *(const float4*)&sC[rr * HID + c4];
      __half2 h0 = __floats2half2_rn(v.x, v.y);
      __half2 h1 = __floats2half2_rn(v.z, v.w);
      uint2 u;
      u.x = *(unsigned*)&h0;
      u.y = *(unsigned*)&h1;
      *(uint2*)(C16 + (size_t)grow * HID + c4) = u;
    }
  }
}

template <bool A16>
__global__ __launch_bounds__(256) void gemm_kernel(const void* __restrict__ A,
                                                   const unsigned short* __restrict__ WhT,
                                                   const unsigned short* __restrict__ WlT,
                                                   __half* __restrict__ C16, int M) {
  gemm_mfma_body<A16>(A, WhT, WlT, nullptr, C16, M, blockIdx.x * GBM);
}

// ---------- fill phase: 4 atomics in flight per thread ----------
__device__ __forceinline__ void fill_phase(const int* __restrict__ ei,
                                           int* __restrict__ fillcnt,
                                           int* __restrict__ col_fixed,
                                           int* __restrict__ ovf_cnt,
                                           int* __restrict__ ovf,
                                           const int* __restrict__ flag,
                                           int e0, int e1) {
  int base = e0 + blockIdx.x * (256 * EPT);
  if (base >= e1) return;
  int is64 = flag[0];
  int tid = threadIdx.x;
  int dsts[EPT], srcs[EPT], pos[EPT];
#pragma unroll
  for (int u = 0; u < EPT; ++u) {
    int e = base + u * 256 + tid;
    if (e < e1) {
      dsts[u] = ld_idx(ei, N_EDGES + e, is64);
      srcs[u] = ld_idx(ei, e, is64);
    } else {
      dsts[u] = -1; srcs[u] = 0;
    }
  }
#pragma unroll
  for (int u = 0; u < EPT; ++u)
    pos[u] = (dsts[u] >= 0) ? atomicAdd(&fillcnt[dsts[u]], 1) : 0;
#pragma unroll
  for (int u = 0; u < EPT; ++u) {
    if (dsts[u] >= 0) {
      if (pos[u] < CAP) {
        col_fixed[dsts[u] * CAP + pos[u]] = srcs[u];
      } else {
        int o = atomicAdd(ovf_cnt, 1);
        if (o < OVF_MAX) { ovf[2 * o] = dsts[u]; ovf[2 * o + 1] = srcs[u]; }
      }
    }
  }
}

template <bool A16>
__global__ __launch_bounds__(256) void gemm_fill_kernel(const void* __restrict__ A,
                                                        const unsigned short* __restrict__ WhT,
                                                        const unsigned short* __restrict__ WlT,
                                                        const float* __restrict__ bias,
                                                        __half* __restrict__ C16,
                                                        const int* __restrict__ ei,
                                                        int* __restrict__ fillcnt,
                                                        int* __restrict__ col_fixed,
                                                        int* __restrict__ ovf_cnt,
                                                        int* __restrict__ ovf,
                                                        const int* __restrict__ flag,
                                                        int e0, int e1) {
  if (blockIdx.x & 1) {
    fill_phase(ei, fillcnt, col_fixed, ovf_cnt, ovf, flag, e0, e1);
    gemm_mfma_body<A16>(A, WhT, WlT, bias, C16, N_NODES, blockIdx.x * GBM);
  } else {
    gemm_mfma_body<A16>(A, WhT, WlT, bias, C16, N_NODES, blockIdx.x * GBM);
    fill_phase(ei, fillcnt, col_fixed, ovf_cnt, ovf, flag, e0, e1);
  }
}

// ---------- agg v8: 16-lane groups x 4 nbrs, uint4 loads, 3-deep rotating prefetch ----------
template <bool FIRST>
__global__ __launch_bounds__(256) void agg_kernel(const __half* __restrict__ xw,
                                                  const int* __restrict__ fillcnt,
                                                  const int* __restrict__ col_fixed,
                                                  float* __restrict__ ew,
                                                  const float* __restrict__ bias,
                                                  const int* __restrict__ ovf_cnt,
                                                  const int* __restrict__ ovf,
                                                  __half* __restrict__ out) {
  int wave = threadIdx.x >> 6;
  int lane = threadIdx.x & 63;
  int node = blockIdx.x * 4 + wave;
  if (node >= N_NODES) return;
  int g = lane >> 4;
  int q = lane & 15;

  const uint4* x4 = (const uint4*)xw;
  int deg = fillcnt[node];
  int m = min(deg, CAP);
  float dd = rsqrtf(1.0f + (float)deg);
  float acc[8];
#pragma unroll
  for (int i = 0; i < 8; ++i) acc[i] = 0.f;

  if (g == 0) {
    float sn = dd * dd;
    uint4 raw = x4[(size_t)node * 16 + q];
    float4 f0 = h4_to_f4(make_uint2(raw.x, raw.y));
    float4 f1 = h4_to_f4(make_uint2(raw.z, raw.w));
    float4 b0 = ((const float4*)bias)[2 * q];
    float4 b1 = ((const float4*)bias)[2 * q + 1];
    acc[0] = f0.x * sn + b0.x; acc[1] = f0.y * sn + b0.y;
    acc[2] = f0.z * sn + b0.z; acc[3] = f0.w * sn + b0.w;
    acc[4] = f1.x * sn + b1.x; acc[5] = f1.y * sn + b1.y;
    acc[6] = f1.z * sn + b1.z; acc[7] = f1.w * sn + b1.w;
  }

  int cidx = node;
  float cw = 0.f;
  if (lane < m) {
    cidx = col_fixed[node * CAP + lane];
    if (FIRST) {
      cw = rsqrtf(1.0f + (float)fillcnt[cidx]) * dd;
      ew[node * CAP + lane] = cw;
    } else {
      cw = ew[node * CAP + lane];
    }
  }

#define GFETCH(JJ, BUF, WB)                                                              \
  {                                                                                      \
    int _sg = min((JJ) + g, 63);                                                         \
    int _src = __builtin_amdgcn_ds_bpermute(_sg << 2, cidx);                             \
    WB = __uint_as_float((unsigned)__builtin_amdgcn_ds_bpermute(_sg << 2,                \
                                                                (int)__float_as_uint(cw))); \
    BUF = x4[(size_t)_src * 16 + q];                                                     \
  }

  if (m > 0) {
    uint4 b0, b1, b2;
    float w0, w1, w2;
    GFETCH(0, b0, w0);
    GFETCH(4, b1, w1);
    GFETCH(8, b2, w2);
    for (int jj = 0; jj < m; jj += 4) {
      const __half2* ph = (const __half2*)&b0;
#pragma unroll
      for (int t = 0; t < 4; ++t) {
        float2 f = __half22float2(ph[t]);
        acc[2 * t] = fmaf(f.x, w0, acc[2 * t]);
        acc[2 * t + 1] = fmaf(f.y, w0, acc[2 * t + 1]);
      }
      b0 = b1; w0 = w1;
      b1 = b2; w1 = w2;
      GFETCH(jj + 12, b2, w2);
    }
  }
#undef GFETCH

  if (deg > CAP && g == 0) {
    int novf = min(*ovf_cnt, OVF_MAX);
    for (int o = 0; o < novf; ++o) {
      if (ovf[2 * o] == node) {
        int src = ovf[2 * o + 1];
        float w = rsqrtf(1.0f + (float)fillcnt[src]) * dd;
        uint4 raw = x4[(size_t)src * 16 + q];
        const __half2* ph = (const __half2*)&raw;
#pragma unroll
        for (int t = 0; t < 4; ++t) {
          float2 f = __half22float2(ph[t]);
          acc[2 * t] = fmaf(f.x, w, acc[2 * t]);
          acc[2 * t + 1] = fmaf(f.y, w, acc[2 * t + 1]);
        }
      }
    }
  }

#pragma unroll
  for (int i = 0; i < 8; ++i) {
    acc[i] += __shfl_xor(acc[i], 16, 64);
    acc[i] += __shfl_xor(acc[i], 32, 64);
  }

  if (g == 0) {
#pragma unroll
    for (int i = 0; i < 8; ++i) acc[i] = fmaxf(acc[i], 0.f);
    __half2 p0 = __floats2half2_rn(acc[0], acc[1]);
    __half2 p1 = __floats2half2_rn(acc[2], acc[3]);
    __half2 p2 = __floats2half2_rn(acc[4], acc[5]);
    __half2 p3 = __floats2half2_rn(acc[6], acc[7]);
    uint4 u;
    u.x = *(unsigned*)&p0; u.y = *(unsigned*)&p1;
    u.z = *(unsigned*)&p2; u.w = *(unsigned*)&p3;
    ((uint4*)out)[(size_t)node * 16 + q] = u;
  }
}

// ---------- z = h3 @ Wf ----------
__global__ __launch_bounds__(256) void z_kernel(const __half* __restrict__ h,
                                                const float* __restrict__ Wf,
                                                float* __restrict__ z, int M) {
  __shared__ float sW[HID * OUTD];
  int tid = threadIdx.x;
  for (int i = tid; i < HID * OUTD; i += 256) sW[i] = Wf[i];
  __syncthreads();
  int row = blockIdx.x * 256 + tid;
  if (row >= M) return;
  float y[OUTD];
#pragma unroll
  for (int o = 0; o < OUTD; ++o) y[o] = 0.f;
  const uint4* hr = (const uint4*)(h + (size_t)row * HID);
  for (int k8 = 0; k8 < 16; ++k8) {
    uint4 raw = hr[k8];
    float4 h0 = h4_to_f4(make_uint2(raw.x, raw.y));
    float4 h1 = h4_to_f4(make_uint2(raw.z, raw.w));
    int kb = k8 * 8;
#pragma unroll
    for (int o = 0; o < OUTD; ++o) {
      y[o] += h0.x * sW[(kb + 0) * OUTD + o];
      y[o] += h0.y * sW[(kb + 1) * OUTD + o];
      y[o] += h0.z * sW[(kb + 2) * OUTD + o];
      y[o] += h0.w * sW[(kb + 3) * OUTD + o];
      y[o] += h1.x * sW[(kb + 4) * OUTD + o];
      y[o] += h1.y * sW[(kb + 5) * OUTD + o];
      y[o] += h1.z * sW[(kb + 6) * OUTD + o];
      y[o] += h1.w * sW[(kb + 7) * OUTD + o];
    }
  }
#pragma unroll
  for (int o = 0; o < OUTD; ++o) z[(size_t)row * OUTD + o] = y[o];
}

// ---------- last hop in 10-dim + pooling + fused finalize ----------
__global__ __launch_bounds__(256) void agg10_kernel(const float* __restrict__ z,
                                                    const int* __restrict__ fillcnt,
                                                    const int* __restrict__ col_fixed,
                                                    const float* __restrict__ ew,
                                                    const float* __restrict__ bf,
                                                    const int* __restrict__ ovf_cnt,
                                                    const int* __restrict__ ovf,
                                                    const int* __restrict__ batch,
                                                    float* __restrict__ pool,
                                                    float* __restrict__ cnt,
                                                    const int* __restrict__ flag,
                                                    int* __restrict__ done_cnt,
                                                    float* __restrict__ out) {
  __shared__ float spool[NGRAPH * OUTD];
  __shared__ float scount[NGRAPH];
  __shared__ int lastflag;
  int tid = threadIdx.x;
  for (int i = tid; i < NGRAPH * OUTD; i += 256) spool[i] = 0.f;
  if (tid < NGRAPH) scount[tid] = 0.f;
  __syncthreads();

  int is64 = flag[0];
  int node = blockIdx.x * 256 + tid;
  bool valid = node < N_NODES;
  int nc = valid ? node : (N_NODES - 1);
  int g = ld_idx(batch, nc, is64);

  float acc[OUTD];
#pragma unroll
  for (int o = 0; o < OUTD; ++o) acc[o] = 0.f;
  float c = 0.f;

  if (valid) {
    int deg = fillcnt[node];
    float sn = 1.0f / (1.0f + (float)deg);
#pragma unroll
    for (int o = 0; o < OUTD; ++o) acc[o] = z[(size_t)node * OUTD + o] * sn + bf[o];
    c = 1.f;

    int m = min(deg, CAP);
    for (int j = 0; j < m; ++j) {
      int src = col_fixed[node * CAP + j];
      float w = ew[node * CAP + j];
      const float2* zr = (const float2*)(z + (size_t)src * OUTD);
#pragma unroll
      for (int p = 0; p < 5; ++p) {
        float2 u = zr[p];
        acc[2 * p] += u.x * w;
        acc[2 * p + 1] += u.y * w;
      }
    }
    if (deg > CAP) {
      int novf = min(*ovf_cnt, OVF_MAX);
      float dd = rsqrtf(1.0f + (float)deg);
      for (int o = 0; o < novf; ++o) {
        if (ovf[2 * o] == node) {
          int src = ovf[2 * o + 1];
          float w = rsqrtf(1.0f + (float)fillcnt[src]) * dd;
#pragma unroll
          for (int qq = 0; qq < OUTD; ++qq) acc[qq] += z[(size_t)src * OUTD + qq] * w;
        }
      }
    }
  }

  int g0 = __builtin_amdgcn_readfirstlane(g);
  unsigned long long same = __ballot(g == g0);
  unsigned long long act = __ballot(1);
  if (same == act) {
#pragma unroll
    for (int off = 1; off < 64; off <<= 1) {
#pragma unroll
      for (int o = 0; o < OUTD; ++o) acc[o] += __shfl_xor(acc[o], off, 64);
      c += __shfl_xor(c, off, 64);
    }
    if ((tid & 63) == 0) {
#pragma unroll
      for (int o = 0; o < OUTD; ++o) atomicAdd(&spool[g0 * OUTD + o], acc[o]);
      atomicAdd(&scount[g0], c);
    }
  } else if (valid) {
#pragma unroll
    for (int o = 0; o < OUTD; ++o) atomicAdd(&spool[g * OUTD + o], acc[o]);
    atomicAdd(&scount[g], 1.f);
  }
  __syncthreads();
  for (int i = tid; i < NGRAPH * OUTD; i += 256) {
    float v = spool[i];
    if (v != 0.f) atomicAdd(&pool[i], v);
  }
  if (tid < NGRAPH && scount[tid] != 0.f) atomicAdd(&cnt[tid], scount[tid]);

  __threadfence();
  if (tid == 0) {
    int t = atomicAdd(done_cnt, 1);
    lastflag = (t == (int)gridDim.x - 1);
  }
  __syncthreads();
  if (lastflag) {
    __threadfence();
    for (int i = tid; i < NGRAPH * OUTD; i += 256) {
      float cc = cnt[i / OUTD];
      out[i] = pool[i] / fmaxf(cc, 1.0f);
    }
  }
}

extern "C" void kernel_launch(void* const* d_in, const int* in_sizes, int n_in,
                              void* d_out, int out_size, void* d_ws, size_t ws_size,
                              hipStream_t stream) {
  const float* x      = (const float*)d_in[0];
  const int*   ei     = (const int*)d_in[1];
  const int*   batch  = (const int*)d_in[2];
  const float* W_in   = (const float*)d_in[3];
  const float* b_in   = (const float*)d_in[4];
  const float* W_hops = (const float*)d_in[5];
  const float* b_hops = (const float*)d_in[6];
  const float* W_cls  = (const float*)d_in[7];
  const float* b_cls  = (const float*)d_in[8];
  float* out = (float*)d_out;

  char* ws = (char*)d_ws;
  size_t off = 0;
  auto alloc = [&](size_t bytes) -> void* {
    void* p = ws + off;
    off += (bytes + 255) & ~(size_t)255;
    return p;
  };

  // zero-initialized region first
  int*   fillcnt = (int*)alloc(N_NODES * 4);
  int*   ovf_cnt = (int*)alloc(4);
  float* pool    = (float*)alloc(NGRAPH * OUTD * 4);
  float* cnt     = (float*)alloc(NGRAPH * 4);
  int*   done_cnt = (int*)alloc(4);
  size_t zero_bytes = off;
  int*   flag    = (int*)alloc(4);
  int*   ovf     = (int*)alloc(OVF_MAX * 2 * 4);
  int*   col_fixed = (int*)alloc((size_t)N_NODES * CAP * 4);
  float* ew      = (float*)alloc((size_t)N_NODES * CAP * 4);
  __half* bufH   = (__half*)alloc((size_t)N_NODES * HID * 2);
  __half* bufX   = (__half*)alloc((size_t)N_NODES * HID * 2);
  float* z       = (float*)alloc((size_t)N_NODES * OUTD * 4);
  float* Wf      = (float*)alloc(HID * OUTD * 4);
  float* bf      = (float*)alloc(16 * 4);
  unsigned short* WhiT = (unsigned short*)alloc(4 * HID * HID * 2);
  unsigned short* WloT = (unsigned short*)alloc(4 * HID * HID * 2);
  (void)ws_size; (void)in_sizes; (void)n_in; (void)out_size;

  hipMemsetAsync(d_ws, 0, zero_bytes, stream);
  setup_kernel<<<6, 256, 0, stream>>>(ei, W_in, W_hops, W_cls,
                                      b_hops + 3 * HID, b_cls,
                                      flag, WhiT, WloT, Wf, bf);

  const int gblocks = (N_NODES + GBM - 1) / GBM;   // 782
  const int ablocks = (N_NODES + 3) / 4;
  const int EHALF = N_EDGES / 2;
  const int WW = HID * HID;

  // encoder (x fp32 -> h0 fp16) + first half of edge placement
  gemm_fill_kernel<false><<<gblocks, 256, 0, stream>>>(x, WhiT, WloT, b_in, bufH,
                                                       ei, fillcnt, col_fixed, ovf_cnt, ovf,
                                                       flag, 0, EHALF);
  // hop-1 GEMM (fp16 direct) + second half of edge placement
  gemm_fill_kernel<true><<<gblocks, 256, 0, stream>>>(bufH, WhiT + WW, WloT + WW, nullptr,
                                                      bufX,
                                                      ei, fillcnt, col_fixed, ovf_cnt, ovf,
                                                      flag, EHALF, N_EDGES);
  // hop 1 aggregate (builds ew)
  agg_kernel<true><<<ablocks, 256, 0, stream>>>(bufX, fillcnt, col_fixed, ew,
                                                b_hops, ovf_cnt, ovf, bufH);
  // hop 2
  gemm_kernel<true><<<gblocks, 256, 0, stream>>>(bufH, WhiT + 2 * WW, WloT + 2 * WW,
                                                 bufX, N_NODES);
  agg_kernel<false><<<ablocks, 256, 0, stream>>>(bufX, fillcnt, col_fixed, ew,
                                                 b_hops + HID, ovf_cnt, ovf, bufH);
  // hop 3
  gemm_kernel<true><<<gblocks, 256, 0, stream>>>(bufH, WhiT + 3 * WW, WloT + 3 * WW,
                                                 bufX, N_NODES);
  agg_kernel<false><<<ablocks, 256, 0, stream>>>(bufX, fillcnt, col_fixed, ew,
                                                 b_hops + 2 * HID, ovf_cnt, ovf, bufH);
  // z = relu(h3) @ Wf
  int nb = (N_NODES + 255) / 256;
  z_kernel<<<nb, 256, 0, stream>>>(bufH, Wf, z, N_NODES);
  // hop 4 folded through classifier in 10-dim + pooling + fused finalize
  agg10_kernel<<<nb, 256, 0, stream>>>(z, fillcnt, col_fixed, ew, bf,
                                       ovf_cnt, ovf, batch, pool, cnt, flag,
                                       done_cnt, out);
}